// Round 5
// baseline (829.264 us; speedup 1.0000x reference)
//
#include <hip/hip_runtime.h>
#include <math.h>

#define NBLK 512
#define THR  256
#define EPSF 1e-8f

__device__ __forceinline__ float sigmoidf_(float x) { return 1.0f / (1.0f + expf(-x)); }
__device__ __forceinline__ float softplusf_(float x) { return fmaxf(x, 0.0f) + log1pf(expf(-fabsf(x))); }
__device__ __forceinline__ float4 ld4(const float* p) { return *(const float4*)p; }

struct Args {
    const float *in_data, *memory, *h_prev, *c_prev, *prev_reads, *prev_weights;
    const float *W_ih, *b_ih, *W_hh, *b_hh, *W_out, *b_out;
    const float *Wk, *bk, *Wbeta, *bbeta, *Wg, *bg, *Ws3, *bs3, *Wgam, *bgam, *We, *be, *Wa, *ba;
    float *gates, *cbuf, *hbuf, *keys, *pbeta, *pg, *pgam, *psA, *eA, *aA;
    float *sims, *wbuf, *rbuf, *out;
    int *bar_g, *bar_r, *bar_s, *bar_f;
};

union SMem {
    struct { float wg[4096]; float red[256]; } w;
    struct { float A[32 * 65]; float W[32 * 33]; } g;
    struct { float part[16][64]; } s;
};

// ---- hierarchical grid barrier: relaxed spins, group-flag relay ----
// 32 groups x 16 blocks. Only the last-arriving block per group polls the
// global flag (<=32 pollers on that line); others poll their group's flag
// line (<=15 pollers). One RELEASE fence at arrival, one ACQUIRE at exit.
__device__ __forceinline__ void gridbar(const Args& a, int k) {
    __syncthreads();
    if (threadIdx.x == 0) {
        __builtin_amdgcn_fence(__ATOMIC_RELEASE, "agent");
        int g = blockIdx.x & 31;
        int* garr  = &a.bar_g[g << 5];
        int* gflag = &a.bar_f[g << 5];
        if (__hip_atomic_fetch_add(garr, 1, __ATOMIC_RELAXED, __HIP_MEMORY_SCOPE_AGENT) == k * 16 - 1) {
            // group leader (last arriver in group)
            if (__hip_atomic_fetch_add(a.bar_r, 1, __ATOMIC_RELAXED, __HIP_MEMORY_SCOPE_AGENT) == k * 32 - 1) {
                __hip_atomic_store(a.bar_s, k, __ATOMIC_RELAXED, __HIP_MEMORY_SCOPE_AGENT);
            }
            while (__hip_atomic_load(a.bar_s, __ATOMIC_RELAXED, __HIP_MEMORY_SCOPE_AGENT) < k)
                __builtin_amdgcn_s_sleep(8);
            __hip_atomic_store(gflag, k, __ATOMIC_RELAXED, __HIP_MEMORY_SCOPE_AGENT);
        } else {
            while (__hip_atomic_load(gflag, __ATOMIC_RELAXED, __HIP_MEMORY_SCOPE_AGENT) < k)
                __builtin_amdgcn_s_sleep(8);
        }
        __builtin_amdgcn_fence(__ATOMIC_ACQUIRE, "agent");
    }
    __syncthreads();
}

__device__ float biasHead(const Args& a, int i, int q) {
    if (q < 64)  return a.bk[(i << 6) + q];
    if (q == 64) return a.bbeta[i];
    if (q == 65) return a.bg[i];
    if (q <= 68) return a.bs3[i * 3 + q - 66];
    if (q == 69) return a.bgam[i];
    if (q < 134) return a.be[(i << 6) + q - 70];
    return a.ba[(i << 6) + q - 134];
}

// ---- generic small GEMM phase: C[128,Ncols] = A[128,K] @ W[Ncols,K]^T ----
__device__ float4 gatherA(const Args& a, int mode, int row, int k) {
    if (mode == 0) {
        if (k < 256)      return ld4(a.in_data + row * 256 + k);
        else if (k < 512) { int kk = k - 256; return ld4(a.prev_reads + (size_t)((kk >> 6) * 128 + row) * 64 + (kk & 63)); }
        else              return ld4(a.h_prev + row * 512 + (k - 512));
    } else if (mode == 1) {
        return ld4(a.cbuf + row * 512 + k);
    } else {
        if (k < 512) return ld4(a.hbuf + row * 512 + k);
        int kk = k - 512;
        return ld4(a.rbuf + (size_t)((kk >> 6) * 128 + row) * 64 + (kk & 63));
    }
}

__device__ float4 gatherW(const Args& a, int mode, int o, int k) {
    if (mode == 0) {
        if (k < 512) return ld4(a.W_ih + (size_t)o * 512 + k);
        return ld4(a.W_hh + (size_t)o * 512 + (k - 512));
    } else if (mode == 2) {
        return ld4(a.W_out + (size_t)o * 768 + k);
    } else {
        if (o >= 1584) return make_float4(0.f, 0.f, 0.f, 0.f);
        int i = o / 198, q = o - i * 198;
        if (q < 64)       return ld4(a.Wk + (size_t)((i << 6) + q) * 512 + k);
        else if (q == 64) return ld4(a.Wbeta + (size_t)i * 512 + k);
        else if (q == 65) return ld4(a.Wg + (size_t)i * 512 + k);
        else if (q <= 68) return ld4(a.Ws3 + (size_t)(i * 3 + q - 66) * 512 + k);
        else if (q == 69) return ld4(a.Wgam + (size_t)i * 512 + k);
        else if (q < 134) return ld4(a.We + (size_t)((i << 6) + q - 70) * 512 + k);
        else              return ld4(a.Wa + (size_t)((i << 6) + q - 134) * 512 + k);
    }
}

__device__ void gemm_phase(const Args& a, SMem& sm, int mode, int K, int Ncols, float* C) {
    int ntiles = 2 * (Ncols >> 5);
    int t = threadIdx.x;
    for (int tile = blockIdx.x; tile < ntiles; tile += NBLK) {
        int rb = (tile & 1) * 64;
        int o0 = (tile >> 1) * 32;
        float acc[4][2] = {{0.f, 0.f}, {0.f, 0.f}, {0.f, 0.f}, {0.f, 0.f}};
        for (int k0 = 0; k0 < K; k0 += 32) {
            __syncthreads();
#pragma unroll
            for (int i = 0; i < 2; ++i) {
                int idx = t + THR * i;
                int row = idx >> 3, c4 = (idx & 7) * 4;
                float4 v = gatherA(a, mode, rb + row, k0 + c4);
                sm.g.A[(c4 + 0) * 65 + row] = v.x;
                sm.g.A[(c4 + 1) * 65 + row] = v.y;
                sm.g.A[(c4 + 2) * 65 + row] = v.z;
                sm.g.A[(c4 + 3) * 65 + row] = v.w;
            }
            {
                int o = t >> 3, c4 = (t & 7) * 4;
                float4 v = gatherW(a, mode, o0 + o, k0 + c4);
                sm.g.W[(c4 + 0) * 33 + o] = v.x;
                sm.g.W[(c4 + 1) * 33 + o] = v.y;
                sm.g.W[(c4 + 2) * 33 + o] = v.z;
                sm.g.W[(c4 + 3) * 33 + o] = v.w;
            }
            __syncthreads();
            int ob = (t & 7) * 4, bb = (t >> 3) * 2;
#pragma unroll
            for (int kk = 0; kk < 32; ++kk) {
                const float* wp = &sm.g.W[kk * 33 + ob];
                const float* ap = &sm.g.A[kk * 65 + bb];
                float a0 = ap[0], a1 = ap[1];
                float w0 = wp[0], w1 = wp[1], w2 = wp[2], w3 = wp[3];
                acc[0][0] = fmaf(w0, a0, acc[0][0]); acc[0][1] = fmaf(w0, a1, acc[0][1]);
                acc[1][0] = fmaf(w1, a0, acc[1][0]); acc[1][1] = fmaf(w1, a1, acc[1][1]);
                acc[2][0] = fmaf(w2, a0, acc[2][0]); acc[2][1] = fmaf(w2, a1, acc[2][1]);
                acc[3][0] = fmaf(w3, a0, acc[3][0]); acc[3][1] = fmaf(w3, a1, acc[3][1]);
            }
        }
        int ob = (t & 7) * 4, bb = (t >> 3) * 2;
        if (mode == 2) {
#pragma unroll
            for (int i = 0; i < 4; ++i)
#pragma unroll
                for (int j = 0; j < 2; ++j)
                    a.out[(size_t)(rb + bb + j) * 256 + o0 + ob + i] =
                        sigmoidf_(acc[i][j] + a.b_out[o0 + ob + i]);
        } else if (mode == 1) {
            // fused head-activation epilogue: scatter by param row q
#pragma unroll
            for (int i = 0; i < 4; ++i) {
                int o = o0 + ob + i;
                if (o >= 1584) continue;
                int ih = o / 198, q = o - ih * 198;
#pragma unroll
                for (int j = 0; j < 2; ++j) {
                    int r = rb + bb + j;        // batch index
                    int hb = ih * 128 + r;
                    float val = acc[i][j] + biasHead(a, ih, q);
                    if (q < 64)        a.keys[(size_t)hb * 64 + q] = val;
                    else if (q == 64)  a.pbeta[hb] = val;
                    else if (q == 65)  a.pg[hb] = val;
                    else if (q <= 68)  a.psA[hb * 3 + (q - 66)] = val;
                    else if (q == 69)  a.pgam[hb] = val;
                    else if (q < 134)  a.eA[(size_t)hb * 64 + (q - 70)] = sigmoidf_(val);
                    else               a.aA[(size_t)hb * 64 + (q - 134)] = tanhf(val);
                }
            }
        } else {
#pragma unroll
            for (int i = 0; i < 4; ++i)
#pragma unroll
                for (int j = 0; j < 2; ++j)
                    C[(size_t)(rb + bb + j) * Ncols + o0 + ob + i] = acc[i][j];
        }
    }
}

// ---- read-only memory sweep; reconstruct states in registers ----
__device__ void sweep_phase(const Args& a, SMem& sm, int napply, int nsims, int sh0, int sh1,
                            int read_state, int read_head, int read_idx) {
    int t = threadIdx.x, lane = t & 15, grp = t >> 4;
    int base = blockIdx.x * 1024;   // 1024 rows/block, 4 blocks per b
    int b = base >> 12;
    int m4 = lane * 4;
    float4 e1 = ld4(a.eA + (size_t)(1 * 128 + b) * 64 + m4);
    float4 a1 = ld4(a.aA + (size_t)(1 * 128 + b) * 64 + m4);
    float4 e3 = ld4(a.eA + (size_t)(3 * 128 + b) * 64 + m4);
    float4 a3 = ld4(a.aA + (size_t)(3 * 128 + b) * 64 + m4);
    float4 e5 = ld4(a.eA + (size_t)(5 * 128 + b) * 64 + m4);
    float4 a5 = ld4(a.aA + (size_t)(5 * 128 + b) * 64 + m4);
    float4 k0v = make_float4(0.f, 0.f, 0.f, 0.f), k1v = k0v;
    float kn0 = 0.f, kn1 = 0.f;
    if (nsims > 0) {
        k0v = ld4(a.keys + (size_t)(sh0 * 128 + b) * 64 + m4);
        float nk = k0v.x * k0v.x + k0v.y * k0v.y + k0v.z * k0v.z + k0v.w * k0v.w;
#pragma unroll
        for (int off = 8; off >= 1; off >>= 1) nk += __shfl_xor(nk, off, 16);
        kn0 = sqrtf(nk);
    }
    if (nsims > 1) {
        k1v = ld4(a.keys + (size_t)(sh1 * 128 + b) * 64 + m4);
        float nk = k1v.x * k1v.x + k1v.y * k1v.y + k1v.z * k1v.z + k1v.w * k1v.w;
#pragma unroll
        for (int off = 8; off >= 1; off >>= 1) nk += __shfl_xor(nk, off, 16);
        kn1 = sqrtf(nk);
    }
    const float* w1p = a.wbuf + (size_t)1 * 128 * 4096;
    const float* w3p = a.wbuf + (size_t)3 * 128 * 4096;
    const float* w5p = a.wbuf + (size_t)5 * 128 * 4096;
    const float* wrp = (read_head >= 0) ? a.wbuf + (size_t)read_head * 128 * 4096 : nullptr;
    float* sim0 = a.sims + (size_t)sh0 * 128 * 4096;
    float* sim1 = a.sims + (size_t)sh1 * 128 * 4096;
    float4 racc = make_float4(0.f, 0.f, 0.f, 0.f);

    auto proc = [&](float4 m, int row) {
        float4 mr = m;
        if (napply >= 1) {
            float w = w1p[row];
            m.x = m.x * (1.f - w * e1.x) + w * a1.x;
            m.y = m.y * (1.f - w * e1.y) + w * a1.y;
            m.z = m.z * (1.f - w * e1.z) + w * a1.z;
            m.w = m.w * (1.f - w * e1.w) + w * a1.w;
            if (read_state == 1) mr = m;
        }
        if (napply >= 2) {
            float w = w3p[row];
            m.x = m.x * (1.f - w * e3.x) + w * a3.x;
            m.y = m.y * (1.f - w * e3.y) + w * a3.y;
            m.z = m.z * (1.f - w * e3.z) + w * a3.z;
            m.w = m.w * (1.f - w * e3.w) + w * a3.w;
            if (read_state == 2) mr = m;
        }
        if (napply >= 3) {
            float w = w5p[row];
            m.x = m.x * (1.f - w * e5.x) + w * a5.x;
            m.y = m.y * (1.f - w * e5.y) + w * a5.y;
            m.z = m.z * (1.f - w * e5.z) + w * a5.z;
            m.w = m.w * (1.f - w * e5.w) + w * a5.w;
            if (read_state == 3) mr = m;
        }
        if (read_head >= 0) {
            float w = wrp[row];
            racc.x = fmaf(w, mr.x, racc.x);
            racc.y = fmaf(w, mr.y, racc.y);
            racc.z = fmaf(w, mr.z, racc.z);
            racc.w = fmaf(w, mr.w, racc.w);
        }
        if (nsims > 0) {
            float d0 = m.x * k0v.x + m.y * k0v.y + m.z * k0v.z + m.w * k0v.w;
            float nn = m.x * m.x + m.y * m.y + m.z * m.z + m.w * m.w;
            float d1 = 0.f;
            if (nsims > 1) d1 = m.x * k1v.x + m.y * k1v.y + m.z * k1v.z + m.w * k1v.w;
#pragma unroll
            for (int off = 8; off >= 1; off >>= 1) {
                d0 += __shfl_xor(d0, off, 16);
                nn += __shfl_xor(nn, off, 16);
                if (nsims > 1) d1 += __shfl_xor(d1, off, 16);
            }
            if (lane == 0) {
                float nm = sqrtf(nn);
                sim0[row] = d0 / (nm * kn0 + EPSF);
                if (nsims > 1) sim1[row] = d1 / (nm * kn1 + EPSF);
            }
        }
    };

    for (int it = 0; it < 64; it += 8) {
        int r0 = base + it * 16 + grp;
        const float* mp = a.memory + (size_t)r0 * 64 + m4;
        float4 m0 = ld4(mp);
        float4 m1 = ld4(mp + 16 * 64);
        float4 m2 = ld4(mp + 32 * 64);
        float4 m3 = ld4(mp + 48 * 64);
        float4 m4_ = ld4(mp + 64 * 64);
        float4 m5 = ld4(mp + 80 * 64);
        float4 m6 = ld4(mp + 96 * 64);
        float4 m7 = ld4(mp + 112 * 64);
        proc(m0, r0);        proc(m1, r0 + 16);  proc(m2, r0 + 32);  proc(m3, r0 + 48);
        proc(m4_, r0 + 64);  proc(m5, r0 + 80);  proc(m6, r0 + 96);  proc(m7, r0 + 112);
    }
    if (read_head >= 0) {
        *(float4*)(&sm.s.part[grp][m4]) = racc;
        __syncthreads();
        if (t < 64) {
            float s = 0.f;
#pragma unroll
            for (int g2 = 0; g2 < 16; ++g2) s += sm.s.part[g2][t];
            atomicAdd(&a.rbuf[(size_t)(read_idx * 128 + b) * 64 + t], s);
        }
    }
}

// ---- softmax(beta*sim) -> interpolate -> shift -> sharpen -> normalize ----
__device__ void weights_phase(const Args& a, SMem& sm, int head0, int nheads) {
    int pair = blockIdx.x;
    if (pair >= nheads * 128) return;
    int h = head0 + (pair >> 7), b = pair & 127;
    int hb = h * 128 + b;
    float beta = softplusf_(a.pbeta[hb]);
    float g = sigmoidf_(a.pg[hb]);
    float gamma = 1.f + softplusf_(a.pgam[hb]);
    float p0 = a.psA[hb * 3 + 0], p1 = a.psA[hb * 3 + 1], p2 = a.psA[hb * 3 + 2];
    float pmx = fmaxf(p0, fmaxf(p1, p2));
    float q0 = expf(p0 - pmx), q1 = expf(p1 - pmx), q2 = expf(p2 - pmx);
    float qinv = 1.f / (q0 + q1 + q2);
    float s0 = q0 * qinv, s1 = q1 * qinv, s2 = q2 * qinv;
    const float* sim = a.sims + (size_t)hb * 4096;
    const float* pw = a.prev_weights + (size_t)hb * 4096;
    float* wout = a.wbuf + (size_t)hb * 4096;
    int t = threadIdx.x;
    float tv[16];
    float lmax = -3.4e38f;
#pragma unroll
    for (int j = 0; j < 16; ++j) {
        float x = beta * sim[t + 256 * j];
        tv[j] = x;
        lmax = fmaxf(lmax, x);
    }
    sm.w.red[t] = lmax; __syncthreads();
    for (int s = 128; s > 0; s >>= 1) { if (t < s) sm.w.red[t] = fmaxf(sm.w.red[t], sm.w.red[t + s]); __syncthreads(); }
    float Mx = sm.w.red[0]; __syncthreads();
    float lsum = 0.f;
#pragma unroll
    for (int j = 0; j < 16; ++j) { float ex = expf(tv[j] - Mx); tv[j] = ex; lsum += ex; }
    sm.w.red[t] = lsum; __syncthreads();
    for (int s = 128; s > 0; s >>= 1) { if (t < s) sm.w.red[t] += sm.w.red[t + s]; __syncthreads(); }
    float invS = 1.f / sm.w.red[0]; __syncthreads();
#pragma unroll
    for (int j = 0; j < 16; ++j) {
        int n = t + 256 * j;
        sm.w.wg[n] = g * tv[j] * invS + (1.f - g) * pw[n];
    }
    __syncthreads();
    float lsum2 = 0.f;
#pragma unroll
    for (int j = 0; j < 16; ++j) {
        int n = t + 256 * j;
        float wsft = s0 * sm.w.wg[(n + 1) & 4095] + s1 * sm.w.wg[n] + s2 * sm.w.wg[(n - 1) & 4095];
        float wp = exp2f(gamma * log2f(wsft));
        tv[j] = wp;
        lsum2 += wp;
    }
    sm.w.red[t] = lsum2; __syncthreads();
    for (int s = 128; s > 0; s >>= 1) { if (t < s) sm.w.red[t] += sm.w.red[t + s]; __syncthreads(); }
    float inv2 = 1.f / (sm.w.red[0] + EPSF);
#pragma unroll
    for (int j = 0; j < 16; ++j) wout[t + 256 * j] = tv[j] * inv2;
}

// ------------------------------------------------------------------
__global__ __launch_bounds__(THR, 2) void ntm_fused(Args a) {
    __shared__ SMem sm;
    int t = threadIdx.x;

    gemm_phase(a, sm, 0, 1024, 2048, a.gates);
    gridbar(a, 1);
    if (blockIdx.x < 256) {
        int idx = blockIdx.x * THR + t;
        int j = idx & 511;
        const float* gr = a.gates + (size_t)(idx >> 9) * 2048;
        float gi = gr[j]        + a.b_ih[j]        + a.b_hh[j];
        float gf = gr[512 + j]  + a.b_ih[512 + j]  + a.b_hh[512 + j];
        float gg = gr[1024 + j] + a.b_ih[1024 + j] + a.b_hh[1024 + j];
        float go = gr[1536 + j] + a.b_ih[1536 + j] + a.b_hh[1536 + j];
        float cc = sigmoidf_(gf) * a.c_prev[idx] + sigmoidf_(gi) * tanhf(gg);
        a.cbuf[idx] = cc;
        a.hbuf[idx] = sigmoidf_(go) * tanhf(cc);
    }
    gridbar(a, 2);
    gemm_phase(a, sm, 1, 512, 1600, nullptr);   // fused head activations
    gridbar(a, 3);
    sweep_phase(a, sm, 0, 2, 0, 1, -1, -1, 0);   gridbar(a, 4);
    weights_phase(a, sm, 0, 2);                  gridbar(a, 5);
    sweep_phase(a, sm, 1, 2, 2, 3, 0, 0, 0);     gridbar(a, 6);
    weights_phase(a, sm, 2, 2);                  gridbar(a, 7);
    sweep_phase(a, sm, 2, 2, 4, 5, 1, 2, 1);     gridbar(a, 8);
    weights_phase(a, sm, 4, 2);                  gridbar(a, 9);
    sweep_phase(a, sm, 3, 1, 6, 6, 2, 4, 2);     gridbar(a, 10);
    weights_phase(a, sm, 6, 1);                  gridbar(a, 11);
    sweep_phase(a, sm, 3, 0, 0, 0, 3, 6, 3);     gridbar(a, 12);
    gemm_phase(a, sm, 2, 768, 256, nullptr);
}

// ------------------------------------------------------------------
extern "C" void kernel_launch(void* const* d_in, const int* in_sizes, int n_in,
                              void* d_out, int out_size, void* d_ws, size_t ws_size,
                              hipStream_t stream) {
    Args a;
    a.in_data      = (const float*)d_in[0];
    a.memory       = (const float*)d_in[1];
    a.h_prev       = (const float*)d_in[2];
    a.c_prev       = (const float*)d_in[3];
    a.prev_reads   = (const float*)d_in[4];
    a.prev_weights = (const float*)d_in[5];
    a.W_ih  = (const float*)d_in[6];
    a.b_ih  = (const float*)d_in[7];
    a.W_hh  = (const float*)d_in[8];
    a.b_hh  = (const float*)d_in[9];
    a.W_out = (const float*)d_in[10];
    a.b_out = (const float*)d_in[11];
    a.Wk    = (const float*)d_in[12];
    a.bk    = (const float*)d_in[13];
    a.Wbeta = (const float*)d_in[14];
    a.bbeta = (const float*)d_in[15];
    a.Wg    = (const float*)d_in[16];
    a.bg    = (const float*)d_in[17];
    a.Ws3   = (const float*)d_in[18];
    a.bs3   = (const float*)d_in[19];
    a.Wgam  = (const float*)d_in[20];
    a.bgam  = (const float*)d_in[21];
    a.We    = (const float*)d_in[22];
    a.be    = (const float*)d_in[23];
    a.Wa    = (const float*)d_in[24];
    a.ba    = (const float*)d_in[25];

    float* ws = (float*)d_ws;
    // zeroed control region: 4096 ints of barrier state + rbuf 32768 floats
    a.bar_g = (int*)ws;              // 32 lines (128B apart)
    a.bar_r = (int*)ws + 1024;
    a.bar_s = (int*)ws + 1088;
    a.bar_f = (int*)ws + 2048;       // 32 lines (128B apart)
    a.rbuf  = ws + 4096;             // [4,128,64]
    size_t off = 4096 + 32768;
    a.gates  = ws + off; off += 262144;   // [128,2048]
    a.cbuf   = ws + off; off += 65536;
    a.hbuf   = ws + off; off += 65536;
    a.keys   = ws + off; off += 65536;    // [8,128,64]
    a.pbeta  = ws + off; off += 1024;
    a.pg     = ws + off; off += 1024;
    a.pgam   = ws + off; off += 1024;
    a.psA    = ws + off; off += 3072;
    a.eA     = ws + off; off += 65536;
    a.aA     = ws + off; off += 65536;
    a.sims   = ws + off; off += 4194304;  // [8,128,4096]
    a.wbuf   = ws + off; off += 4194304;  // [8,128,4096]
    a.out    = (float*)d_out;

    hipMemsetAsync(d_ws, 0, (4096 + 32768) * sizeof(float), stream);
    ntm_fused<<<NBLK, THR, 0, stream>>>(a);

    (void)in_sizes; (void)n_in; (void)out_size; (void)ws_size;
}

// Round 6
// 680.181 us; speedup vs baseline: 1.2192x; 1.2192x over previous
//
#include <hip/hip_runtime.h>
#include <math.h>

#define NBLK 512
#define THR  256
#define EPSF 1e-8f

__device__ __forceinline__ float sigmoidf_(float x) { return 1.0f / (1.0f + expf(-x)); }
__device__ __forceinline__ float softplusf_(float x) { return fmaxf(x, 0.0f) + log1pf(expf(-fabsf(x))); }
__device__ __forceinline__ float4 ld4(const float* p) { return *(const float4*)p; }

// agent-coherent scalar accessors (sc1 path, no cache-maintenance needed)
__device__ __forceinline__ float ldg_a(const float* p) {
    return __hip_atomic_load(p, __ATOMIC_RELAXED, __HIP_MEMORY_SCOPE_AGENT);
}
__device__ __forceinline__ void stg_a(float* p, float v) {
    __hip_atomic_store(p, v, __ATOMIC_RELAXED, __HIP_MEMORY_SCOPE_AGENT);
}
__device__ __forceinline__ float4 ld4_a(const float* p) {
    return make_float4(ldg_a(p), ldg_a(p + 1), ldg_a(p + 2), ldg_a(p + 3));
}

struct Args {
    const float *in_data, *memory, *h_prev, *c_prev, *prev_reads, *prev_weights;
    const float *W_ih, *b_ih, *W_hh, *b_hh, *W_out, *b_out;
    const float *Wk, *bk, *Wbeta, *bbeta, *Wg, *bg, *Ws3, *bs3, *Wgam, *bgam, *We, *be, *Wa, *ba;
    float *gates, *cbuf, *hbuf, *keys, *pbeta, *pg, *pgam, *psA, *eA, *aA;
    float *sims, *wbuf, *rbuf, *out;
    int *bar_g, *bar_r, *bar_f;
};

union SMem {
    struct { float wg[4096]; float red[256]; } w;
    struct { float A[32 * 65]; float W[32 * 33]; } g;
    struct { float part[16][64]; } s;
};

// ---- fence-free grid barrier ----
// All cross-block data uses agent-coherent (sc1) accesses, so no L2
// writeback/invalidate is needed. __syncthreads() drains vmcnt (stores
// complete at LLC) and is a full compiler barrier. Two-level arrive
// (16/group -> 32 groups), final arriver broadcasts to 32 flag lines.
__device__ __forceinline__ void gridbar(const Args& a, int k) {
    __syncthreads();
    if (threadIdx.x == 0) {
        int g = blockIdx.x & 31;
        if (__hip_atomic_fetch_add(&a.bar_g[g << 5], 1, __ATOMIC_RELAXED, __HIP_MEMORY_SCOPE_AGENT) == k * 16 - 1) {
            if (__hip_atomic_fetch_add(a.bar_r, 1, __ATOMIC_RELAXED, __HIP_MEMORY_SCOPE_AGENT) == k * 32 - 1) {
#pragma unroll
                for (int j = 0; j < 32; ++j)
                    __hip_atomic_store(&a.bar_f[j << 5], k, __ATOMIC_RELAXED, __HIP_MEMORY_SCOPE_AGENT);
            }
        }
        while (__hip_atomic_load(&a.bar_f[g << 5], __ATOMIC_RELAXED, __HIP_MEMORY_SCOPE_AGENT) < k)
            __builtin_amdgcn_s_sleep(2);
    }
    __syncthreads();
}

__device__ float biasHead(const Args& a, int i, int q) {
    if (q < 64)  return a.bk[(i << 6) + q];
    if (q == 64) return a.bbeta[i];
    if (q == 65) return a.bg[i];
    if (q <= 68) return a.bs3[i * 3 + q - 66];
    if (q == 69) return a.bgam[i];
    if (q < 134) return a.be[(i << 6) + q - 70];
    return a.ba[(i << 6) + q - 134];
}

// ---- generic small GEMM phase: C[128,Ncols] = A[128,K] @ W[Ncols,K]^T ----
__device__ float4 gatherA(const Args& a, int mode, int row, int k) {
    if (mode == 0) {   // read-only inputs: normal cached loads
        if (k < 256)      return ld4(a.in_data + row * 256 + k);
        else if (k < 512) { int kk = k - 256; return ld4(a.prev_reads + (size_t)((kk >> 6) * 128 + row) * 64 + (kk & 63)); }
        else              return ld4(a.h_prev + row * 512 + (k - 512));
    } else if (mode == 1) {   // cbuf: intermediate -> coherent
        return ld4_a(a.cbuf + row * 512 + k);
    } else {                  // hbuf/rbuf: intermediates -> coherent
        if (k < 512) return ld4_a(a.hbuf + row * 512 + k);
        int kk = k - 512;
        return ld4_a(a.rbuf + (size_t)((kk >> 6) * 128 + row) * 64 + (kk & 63));
    }
}

__device__ float4 gatherW(const Args& a, int mode, int o, int k) {   // all read-only
    if (mode == 0) {
        if (k < 512) return ld4(a.W_ih + (size_t)o * 512 + k);
        return ld4(a.W_hh + (size_t)o * 512 + (k - 512));
    } else if (mode == 2) {
        return ld4(a.W_out + (size_t)o * 768 + k);
    } else {
        if (o >= 1584) return make_float4(0.f, 0.f, 0.f, 0.f);
        int i = o / 198, q = o - i * 198;
        if (q < 64)       return ld4(a.Wk + (size_t)((i << 6) + q) * 512 + k);
        else if (q == 64) return ld4(a.Wbeta + (size_t)i * 512 + k);
        else if (q == 65) return ld4(a.Wg + (size_t)i * 512 + k);
        else if (q <= 68) return ld4(a.Ws3 + (size_t)(i * 3 + q - 66) * 512 + k);
        else if (q == 69) return ld4(a.Wgam + (size_t)i * 512 + k);
        else if (q < 134) return ld4(a.We + (size_t)((i << 6) + q - 70) * 512 + k);
        else              return ld4(a.Wa + (size_t)((i << 6) + q - 134) * 512 + k);
    }
}

__device__ void gemm_phase(const Args& a, SMem& sm, int mode, int K, int Ncols, float* C) {
    int ntiles = 2 * (Ncols >> 5);
    int t = threadIdx.x;
    for (int tile = blockIdx.x; tile < ntiles; tile += NBLK) {
        int rb = (tile & 1) * 64;
        int o0 = (tile >> 1) * 32;
        float acc[4][2] = {{0.f, 0.f}, {0.f, 0.f}, {0.f, 0.f}, {0.f, 0.f}};
        for (int k0 = 0; k0 < K; k0 += 32) {
            __syncthreads();
#pragma unroll
            for (int i = 0; i < 2; ++i) {
                int idx = t + THR * i;
                int row = idx >> 3, c4 = (idx & 7) * 4;
                float4 v = gatherA(a, mode, rb + row, k0 + c4);
                sm.g.A[(c4 + 0) * 65 + row] = v.x;
                sm.g.A[(c4 + 1) * 65 + row] = v.y;
                sm.g.A[(c4 + 2) * 65 + row] = v.z;
                sm.g.A[(c4 + 3) * 65 + row] = v.w;
            }
            {
                int o = t >> 3, c4 = (t & 7) * 4;
                float4 v = gatherW(a, mode, o0 + o, k0 + c4);
                sm.g.W[(c4 + 0) * 33 + o] = v.x;
                sm.g.W[(c4 + 1) * 33 + o] = v.y;
                sm.g.W[(c4 + 2) * 33 + o] = v.z;
                sm.g.W[(c4 + 3) * 33 + o] = v.w;
            }
            __syncthreads();
            int ob = (t & 7) * 4, bb = (t >> 3) * 2;
#pragma unroll
            for (int kk = 0; kk < 32; ++kk) {
                const float* wp = &sm.g.W[kk * 33 + ob];
                const float* ap = &sm.g.A[kk * 65 + bb];
                float a0 = ap[0], a1 = ap[1];
                float w0 = wp[0], w1 = wp[1], w2 = wp[2], w3 = wp[3];
                acc[0][0] = fmaf(w0, a0, acc[0][0]); acc[0][1] = fmaf(w0, a1, acc[0][1]);
                acc[1][0] = fmaf(w1, a0, acc[1][0]); acc[1][1] = fmaf(w1, a1, acc[1][1]);
                acc[2][0] = fmaf(w2, a0, acc[2][0]); acc[2][1] = fmaf(w2, a1, acc[2][1]);
                acc[3][0] = fmaf(w3, a0, acc[3][0]); acc[3][1] = fmaf(w3, a1, acc[3][1]);
            }
        }
        int ob = (t & 7) * 4, bb = (t >> 3) * 2;
        if (mode == 2) {
            // final output: plain stores (kernel-end release covers it)
#pragma unroll
            for (int i = 0; i < 4; ++i)
#pragma unroll
                for (int j = 0; j < 2; ++j)
                    a.out[(size_t)(rb + bb + j) * 256 + o0 + ob + i] =
                        sigmoidf_(acc[i][j] + a.b_out[o0 + ob + i]);
        } else if (mode == 1) {
            // fused head-activation epilogue: coherent scatter by param row q
#pragma unroll
            for (int i = 0; i < 4; ++i) {
                int o = o0 + ob + i;
                if (o >= 1584) continue;
                int ih = o / 198, q = o - ih * 198;
#pragma unroll
                for (int j = 0; j < 2; ++j) {
                    int r = rb + bb + j;
                    int hb = ih * 128 + r;
                    float val = acc[i][j] + biasHead(a, ih, q);
                    if (q < 64)        stg_a(a.keys + (size_t)hb * 64 + q, val);
                    else if (q == 64)  stg_a(a.pbeta + hb, val);
                    else if (q == 65)  stg_a(a.pg + hb, val);
                    else if (q <= 68)  stg_a(a.psA + hb * 3 + (q - 66), val);
                    else if (q == 69)  stg_a(a.pgam + hb, val);
                    else if (q < 134)  stg_a(a.eA + (size_t)hb * 64 + (q - 70), sigmoidf_(val));
                    else               stg_a(a.aA + (size_t)hb * 64 + (q - 134), tanhf(val));
                }
            }
        } else {
#pragma unroll
            for (int i = 0; i < 4; ++i)
#pragma unroll
                for (int j = 0; j < 2; ++j)
                    stg_a(&C[(size_t)(rb + bb + j) * Ncols + o0 + ob + i], acc[i][j]);
        }
    }
}

// ---- read-only memory sweep; reconstruct states in registers ----
__device__ void sweep_phase(const Args& a, SMem& sm, int napply, int nsims, int sh0, int sh1,
                            int read_state, int read_head, int read_idx) {
    int t = threadIdx.x, lane = t & 15, grp = t >> 4;
    int base = blockIdx.x * 1024;   // 1024 rows/block, 4 blocks per b
    int b = base >> 12;
    int m4 = lane * 4;
    float4 e1 = ld4_a(a.eA + (size_t)(1 * 128 + b) * 64 + m4);
    float4 a1 = ld4_a(a.aA + (size_t)(1 * 128 + b) * 64 + m4);
    float4 e3 = ld4_a(a.eA + (size_t)(3 * 128 + b) * 64 + m4);
    float4 a3 = ld4_a(a.aA + (size_t)(3 * 128 + b) * 64 + m4);
    float4 e5 = ld4_a(a.eA + (size_t)(5 * 128 + b) * 64 + m4);
    float4 a5 = ld4_a(a.aA + (size_t)(5 * 128 + b) * 64 + m4);
    float4 k0v = make_float4(0.f, 0.f, 0.f, 0.f), k1v = k0v;
    float kn0 = 0.f, kn1 = 0.f;
    if (nsims > 0) {
        k0v = ld4_a(a.keys + (size_t)(sh0 * 128 + b) * 64 + m4);
        float nk = k0v.x * k0v.x + k0v.y * k0v.y + k0v.z * k0v.z + k0v.w * k0v.w;
#pragma unroll
        for (int off = 8; off >= 1; off >>= 1) nk += __shfl_xor(nk, off, 16);
        kn0 = sqrtf(nk);
    }
    if (nsims > 1) {
        k1v = ld4_a(a.keys + (size_t)(sh1 * 128 + b) * 64 + m4);
        float nk = k1v.x * k1v.x + k1v.y * k1v.y + k1v.z * k1v.z + k1v.w * k1v.w;
#pragma unroll
        for (int off = 8; off >= 1; off >>= 1) nk += __shfl_xor(nk, off, 16);
        kn1 = sqrtf(nk);
    }
    const float* w1p = a.wbuf + (size_t)1 * 128 * 4096;
    const float* w3p = a.wbuf + (size_t)3 * 128 * 4096;
    const float* w5p = a.wbuf + (size_t)5 * 128 * 4096;
    const float* wrp = (read_head >= 0) ? a.wbuf + (size_t)read_head * 128 * 4096 : nullptr;
    float* sim0 = a.sims + (size_t)sh0 * 128 * 4096;
    float* sim1 = a.sims + (size_t)sh1 * 128 * 4096;
    float4 racc = make_float4(0.f, 0.f, 0.f, 0.f);

    auto proc = [&](float4 m, int row) {
        float4 mr = m;
        if (napply >= 1) {
            float w = ldg_a(w1p + row);
            m.x = m.x * (1.f - w * e1.x) + w * a1.x;
            m.y = m.y * (1.f - w * e1.y) + w * a1.y;
            m.z = m.z * (1.f - w * e1.z) + w * a1.z;
            m.w = m.w * (1.f - w * e1.w) + w * a1.w;
            if (read_state == 1) mr = m;
        }
        if (napply >= 2) {
            float w = ldg_a(w3p + row);
            m.x = m.x * (1.f - w * e3.x) + w * a3.x;
            m.y = m.y * (1.f - w * e3.y) + w * a3.y;
            m.z = m.z * (1.f - w * e3.z) + w * a3.z;
            m.w = m.w * (1.f - w * e3.w) + w * a3.w;
            if (read_state == 2) mr = m;
        }
        if (napply >= 3) {
            float w = ldg_a(w5p + row);
            m.x = m.x * (1.f - w * e5.x) + w * a5.x;
            m.y = m.y * (1.f - w * e5.y) + w * a5.y;
            m.z = m.z * (1.f - w * e5.z) + w * a5.z;
            m.w = m.w * (1.f - w * e5.w) + w * a5.w;
            if (read_state == 3) mr = m;
        }
        if (read_head >= 0) {
            float w = ldg_a(wrp + row);
            racc.x = fmaf(w, mr.x, racc.x);
            racc.y = fmaf(w, mr.y, racc.y);
            racc.z = fmaf(w, mr.z, racc.z);
            racc.w = fmaf(w, mr.w, racc.w);
        }
        if (nsims > 0) {
            float d0 = m.x * k0v.x + m.y * k0v.y + m.z * k0v.z + m.w * k0v.w;
            float nn = m.x * m.x + m.y * m.y + m.z * m.z + m.w * m.w;
            float d1 = 0.f;
            if (nsims > 1) d1 = m.x * k1v.x + m.y * k1v.y + m.z * k1v.z + m.w * k1v.w;
#pragma unroll
            for (int off = 8; off >= 1; off >>= 1) {
                d0 += __shfl_xor(d0, off, 16);
                nn += __shfl_xor(nn, off, 16);
                if (nsims > 1) d1 += __shfl_xor(d1, off, 16);
            }
            if (lane == 0) {
                float nm = sqrtf(nn);
                stg_a(sim0 + row, d0 / (nm * kn0 + EPSF));
                if (nsims > 1) stg_a(sim1 + row, d1 / (nm * kn1 + EPSF));
            }
        }
    };

    for (int it = 0; it < 64; it += 8) {
        int r0 = base + it * 16 + grp;
        const float* mp = a.memory + (size_t)r0 * 64 + m4;   // read-only: cached loads
        float4 m0 = ld4(mp);
        float4 m1 = ld4(mp + 16 * 64);
        float4 m2 = ld4(mp + 32 * 64);
        float4 m3 = ld4(mp + 48 * 64);
        float4 m4_ = ld4(mp + 64 * 64);
        float4 m5 = ld4(mp + 80 * 64);
        float4 m6 = ld4(mp + 96 * 64);
        float4 m7 = ld4(mp + 112 * 64);
        proc(m0, r0);        proc(m1, r0 + 16);  proc(m2, r0 + 32);  proc(m3, r0 + 48);
        proc(m4_, r0 + 64);  proc(m5, r0 + 80);  proc(m6, r0 + 96);  proc(m7, r0 + 112);
    }
    if (read_head >= 0) {
        *(float4*)(&sm.s.part[grp][m4]) = racc;
        __syncthreads();
        if (t < 64) {
            float s = 0.f;
#pragma unroll
            for (int g2 = 0; g2 < 16; ++g2) s += sm.s.part[g2][t];
            atomicAdd(&a.rbuf[(size_t)(read_idx * 128 + b) * 64 + t], s);
        }
    }
}

// ---- softmax(beta*sim) -> interpolate -> shift -> sharpen -> normalize ----
__device__ void weights_phase(const Args& a, SMem& sm, int head0, int nheads) {
    int pair = blockIdx.x;
    if (pair >= nheads * 128) return;
    int h = head0 + (pair >> 7), b = pair & 127;
    int hb = h * 128 + b;
    float beta = softplusf_(ldg_a(a.pbeta + hb));
    float g = sigmoidf_(ldg_a(a.pg + hb));
    float gamma = 1.f + softplusf_(ldg_a(a.pgam + hb));
    float p0 = ldg_a(a.psA + hb * 3 + 0), p1 = ldg_a(a.psA + hb * 3 + 1), p2 = ldg_a(a.psA + hb * 3 + 2);
    float pmx = fmaxf(p0, fmaxf(p1, p2));
    float q0 = expf(p0 - pmx), q1 = expf(p1 - pmx), q2 = expf(p2 - pmx);
    float qinv = 1.f / (q0 + q1 + q2);
    float s0 = q0 * qinv, s1 = q1 * qinv, s2 = q2 * qinv;
    const float* sim = a.sims + (size_t)hb * 4096;
    const float* pw = a.prev_weights + (size_t)hb * 4096;   // read-only input: cached
    float* wout = a.wbuf + (size_t)hb * 4096;
    int t = threadIdx.x;
    float tv[16];
    float lmax = -3.4e38f;
#pragma unroll
    for (int j = 0; j < 16; ++j) {
        float x = beta * ldg_a(sim + t + 256 * j);
        tv[j] = x;
        lmax = fmaxf(lmax, x);
    }
    sm.w.red[t] = lmax; __syncthreads();
    for (int s = 128; s > 0; s >>= 1) { if (t < s) sm.w.red[t] = fmaxf(sm.w.red[t], sm.w.red[t + s]); __syncthreads(); }
    float Mx = sm.w.red[0]; __syncthreads();
    float lsum = 0.f;
#pragma unroll
    for (int j = 0; j < 16; ++j) { float ex = expf(tv[j] - Mx); tv[j] = ex; lsum += ex; }
    sm.w.red[t] = lsum; __syncthreads();
    for (int s = 128; s > 0; s >>= 1) { if (t < s) sm.w.red[t] += sm.w.red[t + s]; __syncthreads(); }
    float invS = 1.f / sm.w.red[0]; __syncthreads();
#pragma unroll
    for (int j = 0; j < 16; ++j) {
        int n = t + 256 * j;
        sm.w.wg[n] = g * tv[j] * invS + (1.f - g) * pw[n];
    }
    __syncthreads();
    float lsum2 = 0.f;
#pragma unroll
    for (int j = 0; j < 16; ++j) {
        int n = t + 256 * j;
        float wsft = s0 * sm.w.wg[(n + 1) & 4095] + s1 * sm.w.wg[n] + s2 * sm.w.wg[(n - 1) & 4095];
        float wp = exp2f(gamma * log2f(wsft));
        tv[j] = wp;
        lsum2 += wp;
    }
    sm.w.red[t] = lsum2; __syncthreads();
    for (int s = 128; s > 0; s >>= 1) { if (t < s) sm.w.red[t] += sm.w.red[t + s]; __syncthreads(); }
    float inv2 = 1.f / (sm.w.red[0] + EPSF);
#pragma unroll
    for (int j = 0; j < 16; ++j) stg_a(wout + t + 256 * j, tv[j] * inv2);
}

// ------------------------------------------------------------------
__global__ __launch_bounds__(THR, 2) void ntm_fused(Args a) {
    __shared__ SMem sm;
    int t = threadIdx.x;

    gemm_phase(a, sm, 0, 1024, 2048, a.gates);
    gridbar(a, 1);
    if (blockIdx.x < 256) {
        int idx = blockIdx.x * THR + t;
        int j = idx & 511;
        const float* gr = a.gates + (size_t)(idx >> 9) * 2048;
        float gi = ldg_a(gr + j)        + a.b_ih[j]        + a.b_hh[j];
        float gf = ldg_a(gr + 512 + j)  + a.b_ih[512 + j]  + a.b_hh[512 + j];
        float gg = ldg_a(gr + 1024 + j) + a.b_ih[1024 + j] + a.b_hh[1024 + j];
        float go = ldg_a(gr + 1536 + j) + a.b_ih[1536 + j] + a.b_hh[1536 + j];
        float cc = sigmoidf_(gf) * a.c_prev[idx] + sigmoidf_(gi) * tanhf(gg);
        stg_a(a.cbuf + idx, cc);
        stg_a(a.hbuf + idx, sigmoidf_(go) * tanhf(cc));
    }
    gridbar(a, 2);
    gemm_phase(a, sm, 1, 512, 1600, nullptr);   // fused head activations
    gridbar(a, 3);
    sweep_phase(a, sm, 0, 2, 0, 1, -1, -1, 0);   gridbar(a, 4);
    weights_phase(a, sm, 0, 2);                  gridbar(a, 5);
    sweep_phase(a, sm, 1, 2, 2, 3, 0, 0, 0);     gridbar(a, 6);
    weights_phase(a, sm, 2, 2);                  gridbar(a, 7);
    sweep_phase(a, sm, 2, 2, 4, 5, 1, 2, 1);     gridbar(a, 8);
    weights_phase(a, sm, 4, 2);                  gridbar(a, 9);
    sweep_phase(a, sm, 3, 1, 6, 6, 2, 4, 2);     gridbar(a, 10);
    weights_phase(a, sm, 6, 1);                  gridbar(a, 11);
    sweep_phase(a, sm, 3, 0, 0, 0, 3, 6, 3);     gridbar(a, 12);
    gemm_phase(a, sm, 2, 768, 256, nullptr);
}

// ------------------------------------------------------------------
extern "C" void kernel_launch(void* const* d_in, const int* in_sizes, int n_in,
                              void* d_out, int out_size, void* d_ws, size_t ws_size,
                              hipStream_t stream) {
    Args a;
    a.in_data      = (const float*)d_in[0];
    a.memory       = (const float*)d_in[1];
    a.h_prev       = (const float*)d_in[2];
    a.c_prev       = (const float*)d_in[3];
    a.prev_reads   = (const float*)d_in[4];
    a.prev_weights = (const float*)d_in[5];
    a.W_ih  = (const float*)d_in[6];
    a.b_ih  = (const float*)d_in[7];
    a.W_hh  = (const float*)d_in[8];
    a.b_hh  = (const float*)d_in[9];
    a.W_out = (const float*)d_in[10];
    a.b_out = (const float*)d_in[11];
    a.Wk    = (const float*)d_in[12];
    a.bk    = (const float*)d_in[13];
    a.Wbeta = (const float*)d_in[14];
    a.bbeta = (const float*)d_in[15];
    a.Wg    = (const float*)d_in[16];
    a.bg    = (const float*)d_in[17];
    a.Ws3   = (const float*)d_in[18];
    a.bs3   = (const float*)d_in[19];
    a.Wgam  = (const float*)d_in[20];
    a.bgam  = (const float*)d_in[21];
    a.We    = (const float*)d_in[22];
    a.be    = (const float*)d_in[23];
    a.Wa    = (const float*)d_in[24];
    a.ba    = (const float*)d_in[25];

    float* ws = (float*)d_ws;
    // zeroed control region: barrier state (4096 ints) + rbuf (32768 floats)
    a.bar_g = (int*)ws;              // 32 lines (128B apart)
    a.bar_r = (int*)ws + 1024;
    a.bar_f = (int*)ws + 2048;       // 32 lines (128B apart)
    a.rbuf  = ws + 4096;             // [4,128,64]
    size_t off = 4096 + 32768;
    a.gates  = ws + off; off += 262144;   // [128,2048]
    a.cbuf   = ws + off; off += 65536;
    a.hbuf   = ws + off; off += 65536;
    a.keys   = ws + off; off += 65536;    // [8,128,64]
    a.pbeta  = ws + off; off += 1024;
    a.pg     = ws + off; off += 1024;
    a.pgam   = ws + off; off += 1024;
    a.psA    = ws + off; off += 3072;
    a.eA     = ws + off; off += 65536;
    a.aA     = ws + off; off += 65536;
    a.sims   = ws + off; off += 4194304;  // [8,128,4096]
    a.wbuf   = ws + off; off += 4194304;  // [8,128,4096]
    a.out    = (float*)d_out;

    hipMemsetAsync(d_ws, 0, (4096 + 32768) * sizeof(float), stream);
    ntm_fused<<<NBLK, THR, 0, stream>>>(a);

    (void)in_sizes; (void)n_in; (void)out_size; (void)ws_size;
}

// Round 7
// 635.512 us; speedup vs baseline: 1.3049x; 1.0703x over previous
//
#include <hip/hip_runtime.h>
#include <math.h>

#define NBLK 512
#define THR  256
#define EPSF 1e-8f

__device__ __forceinline__ float sigmoidf_(float x) { return 1.0f / (1.0f + expf(-x)); }
__device__ __forceinline__ float softplusf_(float x) { return fmaxf(x, 0.0f) + log1pf(expf(-fabsf(x))); }
__device__ __forceinline__ float4 ld4(const float* p) { return *(const float4*)p; }

// agent-coherent scalar accessors (sc1 path, bypass stale L1/L2)
__device__ __forceinline__ float ldg_a(const float* p) {
    return __hip_atomic_load(p, __ATOMIC_RELAXED, __HIP_MEMORY_SCOPE_AGENT);
}
__device__ __forceinline__ void stg_a(float* p, float v) {
    __hip_atomic_store(p, v, __ATOMIC_RELAXED, __HIP_MEMORY_SCOPE_AGENT);
}
__device__ __forceinline__ float4 ld4_a(const float* p) {
    return make_float4(ldg_a(p), ldg_a(p + 1), ldg_a(p + 2), ldg_a(p + 3));
}

struct Args {
    const float *in_data, *memory, *h_prev, *c_prev, *prev_reads, *prev_weights;
    const float *W_ih, *b_ih, *W_hh, *b_hh, *W_out, *b_out;
    const float *Wk, *bk, *Wbeta, *bbeta, *Wg, *bg, *Ws3, *bs3, *Wgam, *bgam, *We, *be, *Wa, *ba;
    float *gates, *cbuf, *hbuf, *keys, *pbeta, *pg, *pgam, *psA, *eA, *aA;
    float *sims, *wbuf, *rbuf, *out;
    int *bar_g, *bar_r, *bar_f;
};

union SMem {
    struct { float wg[4096]; float red[256]; } w;                               // 17408 B
    struct { float A[32 * 65]; float W[32 * 33]; } g;                           // 12544 B
    struct { float w1[1024]; float w3[1024]; float w5[1024]; float wr[1024];
             float part[16][64]; } s;                                           // 20480 B
};

// ---- fence-free grid barrier (R6 design, best so far) ----
__device__ __forceinline__ void gridbar(const Args& a, int k) {
    __syncthreads();
    if (threadIdx.x == 0) {
        int g = blockIdx.x & 31;
        if (__hip_atomic_fetch_add(&a.bar_g[g << 5], 1, __ATOMIC_RELAXED, __HIP_MEMORY_SCOPE_AGENT) == k * 16 - 1) {
            if (__hip_atomic_fetch_add(a.bar_r, 1, __ATOMIC_RELAXED, __HIP_MEMORY_SCOPE_AGENT) == k * 32 - 1) {
#pragma unroll
                for (int j = 0; j < 32; ++j)
                    __hip_atomic_store(&a.bar_f[j << 5], k, __ATOMIC_RELAXED, __HIP_MEMORY_SCOPE_AGENT);
            }
        }
        while (__hip_atomic_load(&a.bar_f[g << 5], __ATOMIC_RELAXED, __HIP_MEMORY_SCOPE_AGENT) < k)
            __builtin_amdgcn_s_sleep(2);
    }
    __syncthreads();
}

__device__ float biasHead(const Args& a, int i, int q) {
    if (q < 64)  return a.bk[(i << 6) + q];
    if (q == 64) return a.bbeta[i];
    if (q == 65) return a.bg[i];
    if (q <= 68) return a.bs3[i * 3 + q - 66];
    if (q == 69) return a.bgam[i];
    if (q < 134) return a.be[(i << 6) + q - 70];
    return a.ba[(i << 6) + q - 134];
}

// ---- generic small GEMM phase: C[128,Ncols] = A[128,K] @ W[Ncols,K]^T ----
__device__ float4 gatherA(const Args& a, int mode, int row, int k) {
    if (mode == 0) {
        if (k < 256)      return ld4(a.in_data + row * 256 + k);
        else if (k < 512) { int kk = k - 256; return ld4(a.prev_reads + (size_t)((kk >> 6) * 128 + row) * 64 + (kk & 63)); }
        else              return ld4(a.h_prev + row * 512 + (k - 512));
    } else if (mode == 1) {
        return ld4_a(a.cbuf + row * 512 + k);
    } else {
        if (k < 512) return ld4_a(a.hbuf + row * 512 + k);
        int kk = k - 512;
        return ld4_a(a.rbuf + (size_t)((kk >> 6) * 128 + row) * 64 + (kk & 63));
    }
}

__device__ float4 gatherW(const Args& a, int mode, int o, int k) {
    if (mode == 0) {
        if (k < 512) return ld4(a.W_ih + (size_t)o * 512 + k);
        return ld4(a.W_hh + (size_t)o * 512 + (k - 512));
    } else if (mode == 2) {
        return ld4(a.W_out + (size_t)o * 768 + k);
    } else {
        if (o >= 1584) return make_float4(0.f, 0.f, 0.f, 0.f);
        int i = o / 198, q = o - i * 198;
        if (q < 64)       return ld4(a.Wk + (size_t)((i << 6) + q) * 512 + k);
        else if (q == 64) return ld4(a.Wbeta + (size_t)i * 512 + k);
        else if (q == 65) return ld4(a.Wg + (size_t)i * 512 + k);
        else if (q <= 68) return ld4(a.Ws3 + (size_t)(i * 3 + q - 66) * 512 + k);
        else if (q == 69) return ld4(a.Wgam + (size_t)i * 512 + k);
        else if (q < 134) return ld4(a.We + (size_t)((i << 6) + q - 70) * 512 + k);
        else              return ld4(a.Wa + (size_t)((i << 6) + q - 134) * 512 + k);
    }
}

__device__ void gemm_phase(const Args& a, SMem& sm, int mode, int K, int Ncols, float* C) {
    int ntiles = 2 * (Ncols >> 5);
    int t = threadIdx.x;
    for (int tile = blockIdx.x; tile < ntiles; tile += NBLK) {
        int rb = (tile & 1) * 64;
        int o0 = (tile >> 1) * 32;
        float acc[4][2] = {{0.f, 0.f}, {0.f, 0.f}, {0.f, 0.f}, {0.f, 0.f}};
        for (int k0 = 0; k0 < K; k0 += 32) {
            __syncthreads();
#pragma unroll
            for (int i = 0; i < 2; ++i) {
                int idx = t + THR * i;
                int row = idx >> 3, c4 = (idx & 7) * 4;
                float4 v = gatherA(a, mode, rb + row, k0 + c4);
                sm.g.A[(c4 + 0) * 65 + row] = v.x;
                sm.g.A[(c4 + 1) * 65 + row] = v.y;
                sm.g.A[(c4 + 2) * 65 + row] = v.z;
                sm.g.A[(c4 + 3) * 65 + row] = v.w;
            }
            {
                int o = t >> 3, c4 = (t & 7) * 4;
                float4 v = gatherW(a, mode, o0 + o, k0 + c4);
                sm.g.W[(c4 + 0) * 33 + o] = v.x;
                sm.g.W[(c4 + 1) * 33 + o] = v.y;
                sm.g.W[(c4 + 2) * 33 + o] = v.z;
                sm.g.W[(c4 + 3) * 33 + o] = v.w;
            }
            __syncthreads();
            int ob = (t & 7) * 4, bb = (t >> 3) * 2;
#pragma unroll
            for (int kk = 0; kk < 32; ++kk) {
                const float* wp = &sm.g.W[kk * 33 + ob];
                const float* ap = &sm.g.A[kk * 65 + bb];
                float a0 = ap[0], a1 = ap[1];
                float w0 = wp[0], w1 = wp[1], w2 = wp[2], w3 = wp[3];
                acc[0][0] = fmaf(w0, a0, acc[0][0]); acc[0][1] = fmaf(w0, a1, acc[0][1]);
                acc[1][0] = fmaf(w1, a0, acc[1][0]); acc[1][1] = fmaf(w1, a1, acc[1][1]);
                acc[2][0] = fmaf(w2, a0, acc[2][0]); acc[2][1] = fmaf(w2, a1, acc[2][1]);
                acc[3][0] = fmaf(w3, a0, acc[3][0]); acc[3][1] = fmaf(w3, a1, acc[3][1]);
            }
        }
        int ob = (t & 7) * 4, bb = (t >> 3) * 2;
        if (mode == 2) {
#pragma unroll
            for (int i = 0; i < 4; ++i)
#pragma unroll
                for (int j = 0; j < 2; ++j)
                    a.out[(size_t)(rb + bb + j) * 256 + o0 + ob + i] =
                        sigmoidf_(acc[i][j] + a.b_out[o0 + ob + i]);
        } else if (mode == 1) {
#pragma unroll
            for (int i = 0; i < 4; ++i) {
                int o = o0 + ob + i;
                if (o >= 1584) continue;
                int ih = o / 198, q = o - ih * 198;
#pragma unroll
                for (int j = 0; j < 2; ++j) {
                    int r = rb + bb + j;
                    int hb = ih * 128 + r;
                    float val = acc[i][j] + biasHead(a, ih, q);
                    if (q < 64)        stg_a(a.keys + (size_t)hb * 64 + q, val);
                    else if (q == 64)  stg_a(a.pbeta + hb, val);
                    else if (q == 65)  stg_a(a.pg + hb, val);
                    else if (q <= 68)  stg_a(a.psA + hb * 3 + (q - 66), val);
                    else if (q == 69)  stg_a(a.pgam + hb, val);
                    else if (q < 134)  stg_a(a.eA + (size_t)hb * 64 + (q - 70), sigmoidf_(val));
                    else               stg_a(a.aA + (size_t)hb * 64 + (q - 134), tanhf(val));
                }
            }
        } else {
#pragma unroll
            for (int i = 0; i < 4; ++i)
#pragma unroll
                for (int j = 0; j < 2; ++j)
                    stg_a(&C[(size_t)(rb + bb + j) * Ncols + o0 + ob + i], acc[i][j]);
        }
    }
}

// ---- read-only memory sweep; w-slices staged in LDS (no coherent loads in hot loop) ----
__device__ void sweep_phase(const Args& a, SMem& sm, int napply, int nsims, int sh0, int sh1,
                            int read_state, int read_head, int read_idx) {
    int t = threadIdx.x, lane = t & 15, grp = t >> 4;
    int base = blockIdx.x * 1024;   // 1024 rows/block, 4 blocks per b
    int b = base >> 12;
    int m4 = lane * 4;

    // stage w slices (4 KB each) into LDS: 4 coherent scalar loads per thread
    // per array, all independent -> one LLC latency total per array set.
    {
        int i0 = t * 4;
        if (napply >= 1) {
            const float* p = a.wbuf + (size_t)1 * 524288 + base + i0;
            float x0 = ldg_a(p), x1 = ldg_a(p + 1), x2 = ldg_a(p + 2), x3 = ldg_a(p + 3);
            sm.s.w1[i0] = x0; sm.s.w1[i0 + 1] = x1; sm.s.w1[i0 + 2] = x2; sm.s.w1[i0 + 3] = x3;
        }
        if (napply >= 2) {
            const float* p = a.wbuf + (size_t)3 * 524288 + base + i0;
            float x0 = ldg_a(p), x1 = ldg_a(p + 1), x2 = ldg_a(p + 2), x3 = ldg_a(p + 3);
            sm.s.w3[i0] = x0; sm.s.w3[i0 + 1] = x1; sm.s.w3[i0 + 2] = x2; sm.s.w3[i0 + 3] = x3;
        }
        if (napply >= 3) {
            const float* p = a.wbuf + (size_t)5 * 524288 + base + i0;
            float x0 = ldg_a(p), x1 = ldg_a(p + 1), x2 = ldg_a(p + 2), x3 = ldg_a(p + 3);
            sm.s.w5[i0] = x0; sm.s.w5[i0 + 1] = x1; sm.s.w5[i0 + 2] = x2; sm.s.w5[i0 + 3] = x3;
        }
        if (read_head >= 0) {
            const float* p = a.wbuf + (size_t)read_head * 524288 + base + i0;
            float x0 = ldg_a(p), x1 = ldg_a(p + 1), x2 = ldg_a(p + 2), x3 = ldg_a(p + 3);
            sm.s.wr[i0] = x0; sm.s.wr[i0 + 1] = x1; sm.s.wr[i0 + 2] = x2; sm.s.wr[i0 + 3] = x3;
        }
    }
    __syncthreads();

    float4 e1 = ld4_a(a.eA + (size_t)(1 * 128 + b) * 64 + m4);
    float4 a1 = ld4_a(a.aA + (size_t)(1 * 128 + b) * 64 + m4);
    float4 e3 = ld4_a(a.eA + (size_t)(3 * 128 + b) * 64 + m4);
    float4 a3 = ld4_a(a.aA + (size_t)(3 * 128 + b) * 64 + m4);
    float4 e5 = ld4_a(a.eA + (size_t)(5 * 128 + b) * 64 + m4);
    float4 a5 = ld4_a(a.aA + (size_t)(5 * 128 + b) * 64 + m4);
    float4 k0v = make_float4(0.f, 0.f, 0.f, 0.f), k1v = k0v;
    float kn0 = 0.f, kn1 = 0.f;
    if (nsims > 0) {
        k0v = ld4_a(a.keys + (size_t)(sh0 * 128 + b) * 64 + m4);
        float nk = k0v.x * k0v.x + k0v.y * k0v.y + k0v.z * k0v.z + k0v.w * k0v.w;
#pragma unroll
        for (int off = 8; off >= 1; off >>= 1) nk += __shfl_xor(nk, off, 16);
        kn0 = sqrtf(nk);
    }
    if (nsims > 1) {
        k1v = ld4_a(a.keys + (size_t)(sh1 * 128 + b) * 64 + m4);
        float nk = k1v.x * k1v.x + k1v.y * k1v.y + k1v.z * k1v.z + k1v.w * k1v.w;
#pragma unroll
        for (int off = 8; off >= 1; off >>= 1) nk += __shfl_xor(nk, off, 16);
        kn1 = sqrtf(nk);
    }
    float* sim0 = a.sims + (size_t)sh0 * 524288;
    float* sim1 = a.sims + (size_t)sh1 * 524288;
    float4 racc = make_float4(0.f, 0.f, 0.f, 0.f);

    auto proc = [&](float4 m, int rl) {   // rl = row - base (LDS index)
        float4 mr = m;
        if (napply >= 1) {
            float w = sm.s.w1[rl];
            m.x = m.x * (1.f - w * e1.x) + w * a1.x;
            m.y = m.y * (1.f - w * e1.y) + w * a1.y;
            m.z = m.z * (1.f - w * e1.z) + w * a1.z;
            m.w = m.w * (1.f - w * e1.w) + w * a1.w;
            if (read_state == 1) mr = m;
        }
        if (napply >= 2) {
            float w = sm.s.w3[rl];
            m.x = m.x * (1.f - w * e3.x) + w * a3.x;
            m.y = m.y * (1.f - w * e3.y) + w * a3.y;
            m.z = m.z * (1.f - w * e3.z) + w * a3.z;
            m.w = m.w * (1.f - w * e3.w) + w * a3.w;
            if (read_state == 2) mr = m;
        }
        if (napply >= 3) {
            float w = sm.s.w5[rl];
            m.x = m.x * (1.f - w * e5.x) + w * a5.x;
            m.y = m.y * (1.f - w * e5.y) + w * a5.y;
            m.z = m.z * (1.f - w * e5.z) + w * a5.z;
            m.w = m.w * (1.f - w * e5.w) + w * a5.w;
            if (read_state == 3) mr = m;
        }
        if (read_head >= 0) {
            float w = sm.s.wr[rl];
            racc.x = fmaf(w, mr.x, racc.x);
            racc.y = fmaf(w, mr.y, racc.y);
            racc.z = fmaf(w, mr.z, racc.z);
            racc.w = fmaf(w, mr.w, racc.w);
        }
        if (nsims > 0) {
            float d0 = m.x * k0v.x + m.y * k0v.y + m.z * k0v.z + m.w * k0v.w;
            float nn = m.x * m.x + m.y * m.y + m.z * m.z + m.w * m.w;
            float d1 = 0.f;
            if (nsims > 1) d1 = m.x * k1v.x + m.y * k1v.y + m.z * k1v.z + m.w * k1v.w;
#pragma unroll
            for (int off = 8; off >= 1; off >>= 1) {
                d0 += __shfl_xor(d0, off, 16);
                nn += __shfl_xor(nn, off, 16);
                if (nsims > 1) d1 += __shfl_xor(d1, off, 16);
            }
            if (lane == 0) {
                float nm = sqrtf(nn);
                stg_a(sim0 + base + rl, d0 / (nm * kn0 + EPSF));
                if (nsims > 1) stg_a(sim1 + base + rl, d1 / (nm * kn1 + EPSF));
            }
        }
    };

    for (int it = 0; it < 64; it += 8) {
        int rl0 = it * 16 + grp;
        const float* mp = a.memory + (size_t)(base + rl0) * 64 + m4;   // cached loads
        float4 m0 = ld4(mp);
        float4 m1 = ld4(mp + 16 * 64);
        float4 m2 = ld4(mp + 32 * 64);
        float4 m3 = ld4(mp + 48 * 64);
        float4 m4_ = ld4(mp + 64 * 64);
        float4 m5 = ld4(mp + 80 * 64);
        float4 m6 = ld4(mp + 96 * 64);
        float4 m7 = ld4(mp + 112 * 64);
        proc(m0, rl0);        proc(m1, rl0 + 16);  proc(m2, rl0 + 32);  proc(m3, rl0 + 48);
        proc(m4_, rl0 + 64);  proc(m5, rl0 + 80);  proc(m6, rl0 + 96);  proc(m7, rl0 + 112);
    }
    if (read_head >= 0) {
        __syncthreads();
        *(float4*)(&sm.s.part[grp][m4]) = racc;
        __syncthreads();
        if (t < 64) {
            float s = 0.f;
#pragma unroll
            for (int g2 = 0; g2 < 16; ++g2) s += sm.s.part[g2][t];
            atomicAdd(&a.rbuf[(size_t)(read_idx * 128 + b) * 64 + t], s);
        }
    }
}

// ---- softmax(beta*sim) -> interpolate -> shift -> sharpen -> normalize ----
__device__ void weights_phase(const Args& a, SMem& sm, int head0, int nheads) {
    int pair = blockIdx.x;
    if (pair >= nheads * 128) return;
    int h = head0 + (pair >> 7), b = pair & 127;
    int hb = h * 128 + b;
    float beta = softplusf_(ldg_a(a.pbeta + hb));
    float g = sigmoidf_(ldg_a(a.pg + hb));
    float gamma = 1.f + softplusf_(ldg_a(a.pgam + hb));
    float p0 = ldg_a(a.psA + hb * 3 + 0), p1 = ldg_a(a.psA + hb * 3 + 1), p2 = ldg_a(a.psA + hb * 3 + 2);
    float pmx = fmaxf(p0, fmaxf(p1, p2));
    float q0 = expf(p0 - pmx), q1 = expf(p1 - pmx), q2 = expf(p2 - pmx);
    float qinv = 1.f / (q0 + q1 + q2);
    float s0 = q0 * qinv, s1 = q1 * qinv, s2 = q2 * qinv;
    const float* sim = a.sims + (size_t)hb * 4096;
    const float* pw = a.prev_weights + (size_t)hb * 4096;
    float* wout = a.wbuf + (size_t)hb * 4096;
    int t = threadIdx.x;
    float tv[16];
    float lmax = -3.4e38f;
#pragma unroll
    for (int j = 0; j < 16; ++j) {
        float x = beta * ldg_a(sim + t + 256 * j);
        tv[j] = x;
        lmax = fmaxf(lmax, x);
    }
    sm.w.red[t] = lmax; __syncthreads();
    for (int s = 128; s > 0; s >>= 1) { if (t < s) sm.w.red[t] = fmaxf(sm.w.red[t], sm.w.red[t + s]); __syncthreads(); }
    float Mx = sm.w.red[0]; __syncthreads();
    float lsum = 0.f;
#pragma unroll
    for (int j = 0; j < 16; ++j) { float ex = expf(tv[j] - Mx); tv[j] = ex; lsum += ex; }
    sm.w.red[t] = lsum; __syncthreads();
    for (int s = 128; s > 0; s >>= 1) { if (t < s) sm.w.red[t] += sm.w.red[t + s]; __syncthreads(); }
    float invS = 1.f / sm.w.red[0]; __syncthreads();
#pragma unroll
    for (int j = 0; j < 16; ++j) {
        int n = t + 256 * j;
        sm.w.wg[n] = g * tv[j] * invS + (1.f - g) * pw[n];
    }
    __syncthreads();
    float lsum2 = 0.f;
#pragma unroll
    for (int j = 0; j < 16; ++j) {
        int n = t + 256 * j;
        float wsft = s0 * sm.w.wg[(n + 1) & 4095] + s1 * sm.w.wg[n] + s2 * sm.w.wg[(n - 1) & 4095];
        float wp = exp2f(gamma * log2f(wsft));
        tv[j] = wp;
        lsum2 += wp;
    }
    sm.w.red[t] = lsum2; __syncthreads();
    for (int s = 128; s > 0; s >>= 1) { if (t < s) sm.w.red[t] += sm.w.red[t + s]; __syncthreads(); }
    float inv2 = 1.f / (sm.w.red[0] + EPSF);
#pragma unroll
    for (int j = 0; j < 16; ++j) stg_a(wout + t + 256 * j, tv[j] * inv2);
}

// ------------------------------------------------------------------
__global__ __launch_bounds__(THR, 2) void ntm_fused(Args a) {
    __shared__ SMem sm;
    int t = threadIdx.x;

    gemm_phase(a, sm, 0, 1024, 2048, a.gates);
    gridbar(a, 1);
    if (blockIdx.x < 256) {
        int idx = blockIdx.x * THR + t;
        int j = idx & 511;
        const float* gr = a.gates + (size_t)(idx >> 9) * 2048;
        float gi = ldg_a(gr + j)        + a.b_ih[j]        + a.b_hh[j];
        float gf = ldg_a(gr + 512 + j)  + a.b_ih[512 + j]  + a.b_hh[512 + j];
        float gg = ldg_a(gr + 1024 + j) + a.b_ih[1024 + j] + a.b_hh[1024 + j];
        float go = ldg_a(gr + 1536 + j) + a.b_ih[1536 + j] + a.b_hh[1536 + j];
        float cc = sigmoidf_(gf) * a.c_prev[idx] + sigmoidf_(gi) * tanhf(gg);
        stg_a(a.cbuf + idx, cc);
        stg_a(a.hbuf + idx, sigmoidf_(go) * tanhf(cc));
    }
    gridbar(a, 2);
    gemm_phase(a, sm, 1, 512, 1600, nullptr);   // fused head activations
    gridbar(a, 3);
    sweep_phase(a, sm, 0, 2, 0, 1, -1, -1, 0);   gridbar(a, 4);
    weights_phase(a, sm, 0, 2);                  gridbar(a, 5);
    sweep_phase(a, sm, 1, 2, 2, 3, 0, 0, 0);     gridbar(a, 6);
    weights_phase(a, sm, 2, 2);                  gridbar(a, 7);
    sweep_phase(a, sm, 2, 2, 4, 5, 1, 2, 1);     gridbar(a, 8);
    weights_phase(a, sm, 4, 2);                  gridbar(a, 9);
    sweep_phase(a, sm, 3, 1, 6, 6, 2, 4, 2);     gridbar(a, 10);
    weights_phase(a, sm, 6, 1);                  gridbar(a, 11);
    sweep_phase(a, sm, 3, 0, 0, 0, 3, 6, 3);     gridbar(a, 12);
    gemm_phase(a, sm, 2, 768, 256, nullptr);
}

// ------------------------------------------------------------------
extern "C" void kernel_launch(void* const* d_in, const int* in_sizes, int n_in,
                              void* d_out, int out_size, void* d_ws, size_t ws_size,
                              hipStream_t stream) {
    Args a;
    a.in_data      = (const float*)d_in[0];
    a.memory       = (const float*)d_in[1];
    a.h_prev       = (const float*)d_in[2];
    a.c_prev       = (const float*)d_in[3];
    a.prev_reads   = (const float*)d_in[4];
    a.prev_weights = (const float*)d_in[5];
    a.W_ih  = (const float*)d_in[6];
    a.b_ih  = (const float*)d_in[7];
    a.W_hh  = (const float*)d_in[8];
    a.b_hh  = (const float*)d_in[9];
    a.W_out = (const float*)d_in[10];
    a.b_out = (const float*)d_in[11];
    a.Wk    = (const float*)d_in[12];
    a.bk    = (const float*)d_in[13];
    a.Wbeta = (const float*)d_in[14];
    a.bbeta = (const float*)d_in[15];
    a.Wg    = (const float*)d_in[16];
    a.bg    = (const float*)d_in[17];
    a.Ws3   = (const float*)d_in[18];
    a.bs3   = (const float*)d_in[19];
    a.Wgam  = (const float*)d_in[20];
    a.bgam  = (const float*)d_in[21];
    a.We    = (const float*)d_in[22];
    a.be    = (const float*)d_in[23];
    a.Wa    = (const float*)d_in[24];
    a.ba    = (const float*)d_in[25];

    float* ws = (float*)d_ws;
    a.bar_g = (int*)ws;              // 32 lines (128B apart)
    a.bar_r = (int*)ws + 1024;
    a.bar_f = (int*)ws + 2048;       // 32 lines (128B apart)
    a.rbuf  = ws + 4096;             // [4,128,64]
    size_t off = 4096 + 32768;
    a.gates  = ws + off; off += 262144;   // [128,2048]
    a.cbuf   = ws + off; off += 65536;
    a.hbuf   = ws + off; off += 65536;
    a.keys   = ws + off; off += 65536;    // [8,128,64]
    a.pbeta  = ws + off; off += 1024;
    a.pg     = ws + off; off += 1024;
    a.pgam   = ws + off; off += 1024;
    a.psA    = ws + off; off += 3072;
    a.eA     = ws + off; off += 65536;
    a.aA     = ws + off; off += 65536;
    a.sims   = ws + off; off += 4194304;  // [8,128,4096]
    a.wbuf   = ws + off; off += 4194304;  // [8,128,4096]
    a.out    = (float*)d_out;

    hipMemsetAsync(d_ws, 0, (4096 + 32768) * sizeof(float), stream);
    ntm_fused<<<NBLK, THR, 0, stream>>>(a);

    (void)in_sizes; (void)n_in; (void)out_size; (void)ws_size;
}